// Round 13
// baseline (21883.266 us; speedup 1.0000x reference)
//
#include <hip/hip_runtime.h>
#include <hip/hip_cooperative_groups.h>
#include <cstddef>
#include <cstdint>

namespace cg = cooperative_groups;

namespace {

constexpr int kB  = 4096;   // batch
constexpr int kIN = 4096;
constexpr int kFS = 4096;
constexpr int kS  = 64;
constexpr int kH  = 512;
constexpr int kNG = 2048;   // 4*H
constexpr int kKC = 576;    // 64 (input slice) + 512 (hidden)

typedef __bf16 bf16_t;
typedef __bf16 bfrag  __attribute__((ext_vector_type(8)));
typedef __bf16 bf16v4 __attribute__((ext_vector_type(4)));
typedef float  f32x4  __attribute__((ext_vector_type(4)));

__device__ __forceinline__ void gload16(const void* g, void* l) {
  __builtin_amdgcn_global_load_lds(
      (const __attribute__((address_space(1))) void*)g,
      (__attribute__((address_space(3))) void*)l, 16, 0, 0);
}

__device__ __forceinline__ float sigf(float x) { return 1.0f / (1.0f + __expf(-x)); }
__device__ __forceinline__ float tanh_fast(float x) {
  float e = __expf(2.0f * x);
  return 1.0f - 2.0f / (e + 1.0f);
}

__device__ __forceinline__ f32x4 mfma16(bfrag a, bfrag b, f32x4 c) {
  return __builtin_amdgcn_mfma_f32_16x16x32_bf16(a, b, c, 0, 0, 0);
}

// ---------------- pack kernels ----------------

__global__ __launch_bounds__(256) void f2b4_kernel(const float* __restrict__ in,
                                                   bf16_t* __restrict__ out, int n4) {
  int i = blockIdx.x * 256 + threadIdx.x;
  if (i >= n4) return;
  float4 v = reinterpret_cast<const float4*>(in)[i];
  bf16v4 o = {(bf16_t)v.x, (bf16_t)v.y, (bf16_t)v.z, (bf16_t)v.w};
  *reinterpret_cast<bf16v4*>(out + (size_t)i * 4) = o;
}

// wcat2: MFMA-fragment-order weight pack (verified R9).
__global__ __launch_bounds__(256) void pack_wcat2_kernel(
    const float* __restrict__ Wih_l, const float* __restrict__ Whh_l,
    const float* __restrict__ Wih_r, const float* __restrict__ Whh_r,
    const float* __restrict__ Wih_d, const float* __restrict__ Whh_d,
    bf16_t* __restrict__ wcat2) {
  const int total = 3 * 128 * 9 * 2 * 64 * 8;
  int idx = blockIdx.x * 256 + threadIdx.x;
  if (idx >= total) return;
  int e  = idx & 7;
  int l  = (idx >> 3) & 63;
  int kk = (idx >> 9) & 1;
  int r  = idx >> 10;
  int kt = r % 9;
  int matnb = r / 9;
  int mat = matnb >> 7;
  int nb  = matnb & 127;
  const int c = nb * 16 + (l & 15);
  const int g = (c >> 4) & 3;
  const int u = (c >> 6) * 16 + (c & 15);
  const int orow = g * kH + u;
  const int k = kt * 64 + kk * 32 + (l >> 4) * 8 + e;
  const float* Wih = (mat == 0) ? Wih_l : (mat == 1) ? Wih_r : Wih_d;
  const float* Whh = (mat == 0) ? Whh_l : (mat == 1) ? Whh_r : Whh_d;
  float v = (k < 64) ? Wih[(size_t)orow * 64 + k] : Whh[(size_t)orow * 512 + (k - 64)];
  wcat2[idx] = (bf16_t)v;
}

__global__ __launch_bounds__(256) void pack_bias_kernel(
    const float* __restrict__ bih_l, const float* __restrict__ bhh_l,
    const float* __restrict__ bih_r, const float* __restrict__ bhh_r,
    const float* __restrict__ bih_d, const float* __restrict__ bhh_d,
    float* __restrict__ biasc) {
  int idx = blockIdx.x * 256 + threadIdx.x;
  if (idx >= 3 * kNG) return;
  int mat = idx / kNG;
  int c = idx - mat * kNG;
  int g = (c >> 4) & 3;
  int u = (c >> 6) * 16 + (c & 15);
  int orow = g * kH + u;
  const float* bi = (mat == 0) ? bih_l : (mat == 1) ? bih_r : bih_d;
  const float* bh = (mat == 0) ? bhh_l : (mat == 1) ? bhh_r : bhh_d;
  biasc[idx] = bi[orow] + bh[orow];
}

__global__ __launch_bounds__(256) void pack_h_kernel(const float* __restrict__ h0,
                                                     bf16_t* __restrict__ hbuf0, int n) {
  int i = blockIdx.x * 256 + threadIdx.x;
  if (i >= n) return;
  hbuf0[i] = (bf16_t)h0[i];
}

__global__ __launch_bounds__(256) void transpose64_kernel(const bf16_t* __restrict__ feat,
                                                          bf16_t* __restrict__ featT) {
  __shared__ bf16_t tile[64][65];
  const int b = blockIdx.x;
  const bf16_t* src = feat + (size_t)b * kFS;
  bf16_t* dst = featT + (size_t)b * kFS;
  for (int i = threadIdx.x; i < 4096; i += 256) tile[i >> 6][i & 63] = src[i];
  __syncthreads();
  for (int i = threadIdx.x; i < 4096; i += 256) dst[i] = tile[i & 63][i >> 6];
}

// ---------------- feat GEMM (unchanged, verified) ----------------

__global__ __launch_bounds__(256, 4) void gemm_feat_kernel(
    const bf16_t* __restrict__ X, const bf16_t* __restrict__ W,
    const float* __restrict__ b1, bf16_t* __restrict__ feat) {
  __shared__ bf16_t As[128 * 32];
  __shared__ bf16_t Bs[128 * 32];
  const int t = threadIdx.x;
  const int bid = blockIdx.x;
  const int widx = (bid & 7) * 128 + (bid >> 3);
  const int bm = widx & 31, bn = widx >> 5;
  const int w = t >> 6, l = t & 63;
  const int wm = (w >> 1) * 64, wn = (w & 1) * 64;
  const int sr = t >> 2;
  const int skS = ((t & 3) ^ ((t >> 3) & 3)) * 8;
  const int lr = l & 15;
  const int lkS = ((l >> 4) ^ ((l >> 1) & 3)) * 8;
  const int lrow4 = (l >> 4) * 4;

  f32x4 acc[4][4];
#pragma unroll
  for (int i = 0; i < 4; ++i)
#pragma unroll
    for (int j = 0; j < 4; ++j) acc[i][j] = (f32x4){0.f, 0.f, 0.f, 0.f};

  const bf16_t* ga = X + (size_t)(bm * 128 + sr) * kIN + skS;
  const bf16_t* gb = W + (size_t)(bn * 128 + sr) * kIN + skS;
  bf16_t* lA = As + w * 512;
  bf16_t* lB = Bs + w * 512;

  for (int kt = 0; kt < kIN / 32; ++kt) {
    gload16(ga, lA);
    gload16(ga + (size_t)64 * kIN, lA + 2048);
    gload16(gb, lB);
    gload16(gb + (size_t)64 * kIN, lB + 2048);
    ga += 32; gb += 32;
    __syncthreads();
    bfrag a[4], b[4];
#pragma unroll
    for (int mi = 0; mi < 4; ++mi)
      a[mi] = *reinterpret_cast<const bfrag*>(&As[(wm + mi * 16 + lr) * 32 + lkS]);
#pragma unroll
    for (int ni = 0; ni < 4; ++ni)
      b[ni] = *reinterpret_cast<const bfrag*>(&Bs[(wn + ni * 16 + lr) * 32 + lkS]);
#pragma unroll
    for (int mi = 0; mi < 4; ++mi)
#pragma unroll
      for (int ni = 0; ni < 4; ++ni)
        acc[mi][ni] = __builtin_amdgcn_mfma_f32_16x16x32_bf16(a[mi], b[ni], acc[mi][ni], 0, 0, 0);
    __syncthreads();
  }

#pragma unroll
  for (int ni = 0; ni < 4; ++ni) {
    const int col = bn * 128 + wn + ni * 16 + lr;
    const float bb = b1[col];
#pragma unroll
    for (int mi = 0; mi < 4; ++mi) {
#pragma unroll
      for (int r = 0; r < 4; ++r) {
        const int row = bm * 128 + wm + mi * 16 + lrow4 + r;
        float v = acc[mi][ni][r] + bb;
        feat[(size_t)row * kFS + col] = (bf16_t)fmaxf(v, 0.0f);
      }
    }
  }
}

// ---------------- persistent all-steps kernel (cooperative) ----------------
// 256 blocks x 512 threads, 1 block/CU (co-resident via cooperative launch).
// Per step: 2 jobs (widx, widx+32 -> same cell/bn, bm and bm+4) = 18 K-tiles with
// R9's tile machinery (A via LDS dbuf + T2 swizzle; B direct from wcat2, ping-pong
// regs); epilogue-j1 folded after tile 8; next-step x + B-kt0 prefetched BEFORE the
// grid sync (h-independent, lands during the barrier spin). One grid.sync per step;
// __threadfence() release/acquire handles cross-XCD h visibility. c is NT (keeps the
// per-step wbl2 flush down to h only). h ping-pongs between hbuf slots.

__global__ __launch_bounds__(512, 1) void lstm_persist_kernel(
    const bf16_t* __restrict__ feat, const bf16_t* __restrict__ featT,
    const bf16_t* __restrict__ wcat2, const float* __restrict__ biasc,
    const float* __restrict__ c0, float* __restrict__ cbuf,
    bf16_t* __restrict__ hbuf) {
  cg::grid_group ggrid = cg::this_grid();
  extern __shared__ __align__(16) char smem[];   // 2 x 32 KB A buffers

  const int t = threadIdx.x;
  const int l = t & 63, w = t >> 6;
  const int wr = w >> 2, wc = w & 3;   // 2M x 4N; wave tile 128 x 64
  const int lr = l & 15, lq = l >> 4;
  const int sx = lr & 7;
  const int srow = l >> 3;
  const int sslot = (l & 7) ^ (srow & 7);

  const int bid = blockIdx.x;                    // 256 blocks
  const int widx = (bid & 7) * 64 + (bid >> 3);  // same mapping family as R9
  const int cell = widx >> 7;
  const int rwk = widx & 127;
  const int bmB = rwk >> 3, bn = rwk & 7;        // job jj: bm = bmB + 4*jj

  const bf16_t* xsrc = (cell < 2) ? feat : featT;
  const int mat = (cell < 2) ? cell : 2;
  const size_t HSZc = (size_t)kB * kH;
  const size_t HSZ  = 4 * HSZc;

  auto stageA = [&](int jj, int kt, int buf, const bf16_t* hinc, int off) {
    const int bmr = (bmB + jj * 4) * 256;
    bf16_t* base = (bf16_t*)(smem + buf * 32768);
#pragma unroll
    for (int q = 0; q < 4; ++q) {
      const int row0 = q * 64 + w * 8;           // wave-uniform
      bf16_t* dst = base + row0 * 64;
      const bf16_t* src = (kt == 0)
          ? xsrc + (size_t)(bmr + row0 + srow) * kFS + off + sslot * 8
          : hinc + (size_t)(bmr + row0 + srow) * kH + (kt - 1) * 64 + sslot * 8;
      gload16(src, dst);
    }
  };

  const size_t wb0 = ((size_t)mat * 128 + bn * 16 + wc * 4) * 9;
  auto loadB = [&](int kt, bfrag (&d)[8]) {
#pragma unroll
    for (int nn = 0; nn < 4; ++nn)
#pragma unroll
      for (int kk = 0; kk < 2; ++kk)
        d[nn * 2 + kk] = *reinterpret_cast<const bfrag*>(
            wcat2 + (((wb0 + (size_t)nn * 9 + kt) * 2 + kk) << 9) + l * 8);
  };

  f32x4 acc[8][4];
#pragma unroll
  for (int i = 0; i < 8; ++i)
#pragma unroll
    for (int j = 0; j < 4; ++j) acc[i][j] = (f32x4){0.f, 0.f, 0.f, 0.f};

  bfrag bA[8], bB[8];

  // step-invariant epilogue constants
  const float* biasn = biasc + mat * kNG + bn * 256 + wc * 64;
  const float bb0 = biasn[0 * 16 + lr];
  const float bb1 = biasn[1 * 16 + lr];
  const float bb2 = biasn[2 * 16 + lr];
  const float bb3 = biasn[3 * 16 + lr];
  const int u = (bn * 4 + wc) * 16 + lr;

  auto epi = [&](int jj, int s, bf16_t* hout) {
    const float* csrc = (s == 0) ? c0 : cbuf;
    const int row0 = (bmB + jj * 4) * 256 + wr * 128 + lq * 4;
#pragma unroll
    for (int mi = 0; mi < 8; ++mi) {
#pragma unroll
      for (int j4 = 0; j4 < 4; ++j4) {
        const float iv = sigf(acc[mi][0][j4] + bb0);
        const float fv = sigf(acc[mi][1][j4] + bb1);
        const float gv = tanh_fast(acc[mi][2][j4] + bb2);
        const float ov = sigf(acc[mi][3][j4] + bb3);
        const int row = row0 + mi * 16 + j4;
        const size_t cidx = ((size_t)cell * kB + row) * kH + u;
        const float cold = __builtin_nontemporal_load(&csrc[cidx]);
        const float cn = fv * cold + iv * gv;
        __builtin_nontemporal_store(cn, &cbuf[cidx]);
        hout[cidx] = (bf16_t)(ov * tanh_fast(cn));
      }
#pragma unroll
      for (int nn = 0; nn < 4; ++nn) acc[mi][nn] = (f32x4){0.f, 0.f, 0.f, 0.f};
    }
  };

  // prologue for s=0: x of job1 into buf0 + B kt0
  {
    const int off0 = ((cell & 1) ? 63 : 0) * 64;
    stageA(0, 0, 0, hbuf, off0);
    loadB(0, bA);
    asm volatile("s_waitcnt vmcnt(0)" ::: "memory");
    __builtin_amdgcn_sched_barrier(0);
    __builtin_amdgcn_s_barrier();
  }

#pragma unroll 1
  for (int s = 0; s < 64; ++s) {
    const bf16_t* hinc = hbuf + (size_t)(s & 1) * HSZ + (size_t)cell * HSZc;
    bf16_t* hout = hbuf + (size_t)((s + 1) & 1) * HSZ;
    const int off = ((cell & 1) ? (63 - s) : s) * 64;

#pragma unroll
    for (int gg = 0; gg < 18; ++gg) {
      const int cur = gg & 1;
      const bf16_t* As_ = (const bf16_t*)(smem + cur * 32768);
      bfrag (&bCur)[8] = (gg & 1) ? bB : bA;
      bfrag (&bNxt)[8] = (gg & 1) ? bA : bB;

      if (gg < 17) stageA((gg + 1) / 9, (gg + 1) % 9, cur ^ 1, hinc, off);

      bfrag a[8];
      // ---- sub-burst 1: mi 0..3 ----
#pragma unroll
      for (int mi = 0; mi < 4; ++mi)
#pragma unroll
        for (int kk = 0; kk < 2; ++kk)
          a[mi * 2 + kk] = *reinterpret_cast<const bfrag*>(
              As_ + (wr * 128 + mi * 16 + lr) * 64 + (((kk * 4 + lq) ^ sx) * 8));
      __builtin_amdgcn_s_setprio(1);
#pragma unroll
      for (int kk = 0; kk < 2; ++kk)
#pragma unroll
        for (int mi = 0; mi < 4; ++mi)
#pragma unroll
          for (int nn = 0; nn < 4; ++nn)
            acc[mi][nn] = mfma16(a[mi * 2 + kk], bCur[nn * 2 + kk], acc[mi][nn]);
      __builtin_amdgcn_s_setprio(0);

      loadB((gg + 1) % 9, bNxt);   // gg==8/17 -> kt0 (job2 / next step, same data)

      // ---- sub-burst 2: mi 4..7 ----
#pragma unroll
      for (int mi = 0; mi < 4; ++mi)
#pragma unroll
        for (int kk = 0; kk < 2; ++kk)
          a[mi * 2 + kk] = *reinterpret_cast<const bfrag*>(
              As_ + (wr * 128 + 64 + mi * 16 + lr) * 64 + (((kk * 4 + lq) ^ sx) * 8));
      __builtin_amdgcn_s_setprio(1);
#pragma unroll
      for (int kk = 0; kk < 2; ++kk)
#pragma unroll
        for (int mi = 0; mi < 4; ++mi)
#pragma unroll
          for (int nn = 0; nn < 4; ++nn)
            acc[4 + mi][nn] = mfma16(a[mi * 2 + kk], bCur[nn * 2 + kk], acc[4 + mi][nn]);
      __builtin_amdgcn_s_setprio(0);
      __builtin_amdgcn_sched_barrier(0);

      if (gg < 17) {
        asm volatile("s_waitcnt vmcnt(8)" ::: "memory");  // stage(gg+1) landed
        __builtin_amdgcn_sched_barrier(0);
        __builtin_amdgcn_s_barrier();
        if (gg == 8) epi(0, s, hout);   // job1 done; epilogue overlaps job2 tiles
      }
    }

    epi(1, s, hout);                    // job2 epilogue (also zeroes acc)

    if (s < 63) {
      // prefetch next step's h-independent work before the grid barrier
      const int offn = ((cell & 1) ? (63 - (s + 1)) : (s + 1)) * 64;
      stageA(0, 0, 0, hinc, offn);      // x of job1 into buf0 (18&1==0 parity OK)
      __threadfence();                  // release: vmcnt0 + L2 writeback (h visible)
      ggrid.sync();
      __threadfence();                  // acquire: invalidate stale h lines
      __builtin_amdgcn_s_barrier();     // LDS of prefetched stage visible block-wide
    }
  }
}

// ---------------- head: wave shuffle reduce ----------------

__global__ __launch_bounds__(256) void head_kernel(const bf16_t* __restrict__ hfin,
                                                   const float* __restrict__ W3,
                                                   const float* __restrict__ b3,
                                                   float* __restrict__ out) {
  const int b = blockIdx.x, t = threadIdx.x;
  const int l = t & 63, w = t >> 6;
  float acc[10];
#pragma unroll
  for (int j = 0; j < 10; ++j) acc[j] = 0.f;
  for (int k = t; k < 2048; k += 256) {
    const int cell = k >> 9, u = k & 511;
    const float hv = (float)hfin[((size_t)cell * kB + b) * kH + u];
#pragma unroll
    for (int j = 0; j < 10; ++j) acc[j] += hv * W3[j * 2048 + k];
  }
#pragma unroll
  for (int j = 0; j < 10; ++j)
#pragma unroll
    for (int o = 32; o > 0; o >>= 1) acc[j] += __shfl_down(acc[j], o, 64);
  __shared__ float wred[4][10];
  if (l == 0)
#pragma unroll
    for (int j = 0; j < 10; ++j) wred[w][j] = acc[j];
  __syncthreads();
  if (t == 0) {
    float logits[10];
#pragma unroll
    for (int j = 0; j < 10; ++j)
      logits[j] = wred[0][j] + wred[1][j] + wred[2][j] + wred[3][j] + b3[j];
    float mx = logits[0];
#pragma unroll
    for (int j = 1; j < 10; ++j) mx = fmaxf(mx, logits[j]);
    float se = 0.f;
#pragma unroll
    for (int j = 0; j < 10; ++j) se += expf(logits[j] - mx);
    const float lse = mx + logf(se);
#pragma unroll
    for (int j = 0; j < 10; ++j) out[(size_t)b * 10 + j] = logits[j] - lse;
  }
}

}  // namespace

extern "C" void kernel_launch(void* const* d_in, const int* in_sizes, int n_in,
                              void* d_out, int out_size, void* d_ws, size_t ws_size,
                              hipStream_t stream) {
  const float* x     = (const float*)d_in[0];
  const float* h0    = (const float*)d_in[1];
  const float* c0    = (const float*)d_in[2];
  const float* W1    = (const float*)d_in[3];
  const float* b1    = (const float*)d_in[4];
  const float* Wih_l = (const float*)d_in[5];
  const float* Whh_l = (const float*)d_in[6];
  const float* bih_l = (const float*)d_in[7];
  const float* bhh_l = (const float*)d_in[8];
  const float* Wih_r = (const float*)d_in[9];
  const float* Whh_r = (const float*)d_in[10];
  const float* bih_r = (const float*)d_in[11];
  const float* bhh_r = (const float*)d_in[12];
  const float* Wih_d = (const float*)d_in[13];
  const float* Whh_d = (const float*)d_in[14];
  const float* bih_d = (const float*)d_in[15];
  const float* bhh_d = (const float*)d_in[16];
  const float* W3    = (const float*)d_in[17];
  const float* b3    = (const float*)d_in[18];
  float* out = (float*)d_out;

  char* p = (char*)d_ws;
  auto take = [&](size_t bytes) {
    char* r = p;
    p += (bytes + 255) & ~(size_t)255;
    return r;
  };
  bf16_t* xb    = (bf16_t*)take((size_t)kB * kIN * 2);   // later reused as featT
  bf16_t* w1b   = (bf16_t*)take((size_t)kFS * kIN * 2);  // later reused as hbuf (2 slots)
  bf16_t* feat  = (bf16_t*)take((size_t)kB * kFS * 2);
  bf16_t* wcat2 = (bf16_t*)take((size_t)3 * 128 * 9 * 2 * 64 * 8 * 2);
  float*  biasc = (float*)take((size_t)3 * kNG * 4);
  float*  cbuf  = (float*)take((size_t)4 * kB * kH * 4);
  bf16_t* featT = xb;   // safe: gemm_feat (reads xb) precedes transpose (writes featT)
  bf16_t* hbuf  = w1b;  // safe: gemm_feat (reads w1b) precedes pack_h
  const size_t HSZ = (size_t)4 * kB * kH;

  (void)hipFuncSetAttribute(reinterpret_cast<const void*>(&lstm_persist_kernel),
                            hipFuncAttributeMaxDynamicSharedMemorySize, 65536);

  f2b4_kernel<<<(kB * kIN / 4) / 256, 256, 0, stream>>>(x, xb, kB * kIN / 4);
  f2b4_kernel<<<(kFS * kIN / 4) / 256, 256, 0, stream>>>(W1, w1b, kFS * kIN / 4);
  gemm_feat_kernel<<<dim3(1024), 256, 0, stream>>>(xb, w1b, b1, feat);
  transpose64_kernel<<<kB, 256, 0, stream>>>(feat, featT);
  {
    const int total = 3 * 128 * 9 * 2 * 64 * 8;
    pack_wcat2_kernel<<<(total + 255) / 256, 256, 0, stream>>>(
        Wih_l, Whh_l, Wih_r, Whh_r, Wih_d, Whh_d, wcat2);
  }
  pack_bias_kernel<<<(3 * kNG + 255) / 256, 256, 0, stream>>>(
      bih_l, bhh_l, bih_r, bhh_r, bih_d, bhh_d, biasc);
  pack_h_kernel<<<(int)(HSZ / 256), 256, 0, stream>>>(h0, hbuf, (int)HSZ);

  {
    const bf16_t* a0 = feat;
    const bf16_t* a1 = featT;
    const bf16_t* a2 = wcat2;
    const float*  a3 = biasc;
    const float*  a4 = c0;
    float*        a5 = cbuf;
    bf16_t*       a6 = hbuf;
    void* kargs[] = {&a0, &a1, &a2, &a3, &a4, &a5, &a6};
    (void)hipLaunchCooperativeKernel((const void*)&lstm_persist_kernel,
                                     dim3(256), dim3(512), kargs, 65536, stream);
  }

  head_kernel<<<kB, 256, 0, stream>>>(hbuf, W3, b3, out);  // final h in slot 0
}

// Round 14
// 4265.605 us; speedup vs baseline: 5.1302x; 5.1302x over previous
//
#include <hip/hip_runtime.h>
#include <cstddef>
#include <cstdint>

namespace {

constexpr int kB  = 4096;   // batch
constexpr int kIN = 4096;
constexpr int kFS = 4096;
constexpr int kS  = 64;
constexpr int kH  = 512;
constexpr int kNG = 2048;   // 4*H
constexpr int kKC = 576;    // 64 (input slice) + 512 (hidden)

typedef __bf16 bf16_t;
typedef __bf16 bfrag  __attribute__((ext_vector_type(8)));
typedef __bf16 bf16v4 __attribute__((ext_vector_type(4)));
typedef float  f32x4  __attribute__((ext_vector_type(4)));

__device__ __forceinline__ void gload16(const void* g, void* l) {
  __builtin_amdgcn_global_load_lds(
      (const __attribute__((address_space(1))) void*)g,
      (__attribute__((address_space(3))) void*)l, 16, 0, 0);
}

__device__ __forceinline__ float sigf(float x) { return 1.0f / (1.0f + __expf(-x)); }
__device__ __forceinline__ float tanh_fast(float x) {
  float e = __expf(2.0f * x);
  return 1.0f - 2.0f / (e + 1.0f);
}

__device__ __forceinline__ f32x4 mfma16(bfrag a, bfrag b, f32x4 c) {
  return __builtin_amdgcn_mfma_f32_16x16x32_bf16(a, b, c, 0, 0, 0);
}

// ---------------- pack kernels ----------------

__global__ __launch_bounds__(256) void f2b4_kernel(const float* __restrict__ in,
                                                   bf16_t* __restrict__ out, int n4) {
  int i = blockIdx.x * 256 + threadIdx.x;
  if (i >= n4) return;
  float4 v = reinterpret_cast<const float4*>(in)[i];
  bf16v4 o = {(bf16_t)v.x, (bf16_t)v.y, (bf16_t)v.z, (bf16_t)v.w};
  *reinterpret_cast<bf16v4*>(out + (size_t)i * 4) = o;
}

// wcat2: MFMA-fragment-order weight pack (verified R9).
__global__ __launch_bounds__(256) void pack_wcat2_kernel(
    const float* __restrict__ Wih_l, const float* __restrict__ Whh_l,
    const float* __restrict__ Wih_r, const float* __restrict__ Whh_r,
    const float* __restrict__ Wih_d, const float* __restrict__ Whh_d,
    bf16_t* __restrict__ wcat2) {
  const int total = 3 * 128 * 9 * 2 * 64 * 8;
  int idx = blockIdx.x * 256 + threadIdx.x;
  if (idx >= total) return;
  int e  = idx & 7;
  int l  = (idx >> 3) & 63;
  int kk = (idx >> 9) & 1;
  int r  = idx >> 10;
  int kt = r % 9;
  int matnb = r / 9;
  int mat = matnb >> 7;
  int nb  = matnb & 127;
  const int c = nb * 16 + (l & 15);
  const int g = (c >> 4) & 3;
  const int u = (c >> 6) * 16 + (c & 15);
  const int orow = g * kH + u;
  const int k = kt * 64 + kk * 32 + (l >> 4) * 8 + e;
  const float* Wih = (mat == 0) ? Wih_l : (mat == 1) ? Wih_r : Wih_d;
  const float* Whh = (mat == 0) ? Whh_l : (mat == 1) ? Whh_r : Whh_d;
  float v = (k < 64) ? Wih[(size_t)orow * 64 + k] : Whh[(size_t)orow * 512 + (k - 64)];
  wcat2[idx] = (bf16_t)v;
}

__global__ __launch_bounds__(256) void pack_bias_kernel(
    const float* __restrict__ bih_l, const float* __restrict__ bhh_l,
    const float* __restrict__ bih_r, const float* __restrict__ bhh_r,
    const float* __restrict__ bih_d, const float* __restrict__ bhh_d,
    float* __restrict__ biasc) {
  int idx = blockIdx.x * 256 + threadIdx.x;
  if (idx >= 3 * kNG) return;
  int mat = idx / kNG;
  int c = idx - mat * kNG;
  int g = (c >> 4) & 3;
  int u = (c >> 6) * 16 + (c & 15);
  int orow = g * kH + u;
  const float* bi = (mat == 0) ? bih_l : (mat == 1) ? bih_r : bih_d;
  const float* bh = (mat == 0) ? bhh_l : (mat == 1) ? bhh_r : bhh_d;
  biasc[idx] = bi[orow] + bh[orow];
}

// h0 -> bf16 hbuf; c0 -> bf16 cbuf (c now lives in bf16 between steps)
__global__ __launch_bounds__(256) void pack_hc_kernel(const float* __restrict__ h0,
                                                      const float* __restrict__ c0,
                                                      bf16_t* __restrict__ hbuf0,
                                                      bf16_t* __restrict__ cbuf, int n) {
  int i = blockIdx.x * 256 + threadIdx.x;
  if (i >= n) return;
  hbuf0[i] = (bf16_t)h0[i];
  cbuf[i]  = (bf16_t)c0[i];
}

__global__ __launch_bounds__(256) void transpose64_kernel(const bf16_t* __restrict__ feat,
                                                          bf16_t* __restrict__ featT) {
  __shared__ bf16_t tile[64][65];
  const int b = blockIdx.x;
  const bf16_t* src = feat + (size_t)b * kFS;
  bf16_t* dst = featT + (size_t)b * kFS;
  for (int i = threadIdx.x; i < 4096; i += 256) tile[i >> 6][i & 63] = src[i];
  __syncthreads();
  for (int i = threadIdx.x; i < 4096; i += 256) dst[i] = tile[i & 63][i >> 6];
}

// ---------------- feat GEMM (unchanged, verified) ----------------

__global__ __launch_bounds__(256, 4) void gemm_feat_kernel(
    const bf16_t* __restrict__ X, const bf16_t* __restrict__ W,
    const float* __restrict__ b1, bf16_t* __restrict__ feat) {
  __shared__ bf16_t As[128 * 32];
  __shared__ bf16_t Bs[128 * 32];
  const int t = threadIdx.x;
  const int bid = blockIdx.x;
  const int widx = (bid & 7) * 128 + (bid >> 3);
  const int bm = widx & 31, bn = widx >> 5;
  const int w = t >> 6, l = t & 63;
  const int wm = (w >> 1) * 64, wn = (w & 1) * 64;
  const int sr = t >> 2;
  const int skS = ((t & 3) ^ ((t >> 3) & 3)) * 8;
  const int lr = l & 15;
  const int lkS = ((l >> 4) ^ ((l >> 1) & 3)) * 8;
  const int lrow4 = (l >> 4) * 4;

  f32x4 acc[4][4];
#pragma unroll
  for (int i = 0; i < 4; ++i)
#pragma unroll
    for (int j = 0; j < 4; ++j) acc[i][j] = (f32x4){0.f, 0.f, 0.f, 0.f};

  const bf16_t* ga = X + (size_t)(bm * 128 + sr) * kIN + skS;
  const bf16_t* gb = W + (size_t)(bn * 128 + sr) * kIN + skS;
  bf16_t* lA = As + w * 512;
  bf16_t* lB = Bs + w * 512;

  for (int kt = 0; kt < kIN / 32; ++kt) {
    gload16(ga, lA);
    gload16(ga + (size_t)64 * kIN, lA + 2048);
    gload16(gb, lB);
    gload16(gb + (size_t)64 * kIN, lB + 2048);
    ga += 32; gb += 32;
    __syncthreads();
    bfrag a[4], b[4];
#pragma unroll
    for (int mi = 0; mi < 4; ++mi)
      a[mi] = *reinterpret_cast<const bfrag*>(&As[(wm + mi * 16 + lr) * 32 + lkS]);
#pragma unroll
    for (int ni = 0; ni < 4; ++ni)
      b[ni] = *reinterpret_cast<const bfrag*>(&Bs[(wn + ni * 16 + lr) * 32 + lkS]);
#pragma unroll
    for (int mi = 0; mi < 4; ++mi)
#pragma unroll
      for (int ni = 0; ni < 4; ++ni)
        acc[mi][ni] = __builtin_amdgcn_mfma_f32_16x16x32_bf16(a[mi], b[ni], acc[mi][ni], 0, 0, 0);
    __syncthreads();
  }

#pragma unroll
  for (int ni = 0; ni < 4; ++ni) {
    const int col = bn * 128 + wn + ni * 16 + lr;
    const float bb = b1[col];
#pragma unroll
    for (int mi = 0; mi < 4; ++mi) {
#pragma unroll
      for (int r = 0; r < 4; ++r) {
        const int row = bm * 128 + wm + mi * 16 + lrow4 + r;
        float v = acc[mi][ni][r] + bb;
        feat[(size_t)row * kFS + col] = (bf16_t)fmaxf(v, 0.0f);
      }
    }
  }
}

// ---------------- step kernel: R9 K-loop + coalesced LDS-relayout state path ----------------
// 256x256 tile, 8 waves (2Mx4N, wave 128x64). A via LDS dbuf + T2 swizzle; B direct from
// wcat2 (ping-pong regs). NEW state path: c is bf16; the block's c-tile (256x64 = 32 KB)
// is prefetched into the dead A-buf1 via global_load_lds during the LAST K-tile (128B-
// coalesced); gates computed reading c from LDS; c/h written to LDS tiles (c in place in
// buf1, h into buf0); then a copy-out where 8 consecutive lanes cover one row's 128 B ->
// ALL c/h HBM traffic is >=128B-segment coalesced (was 32-64B per-lane scatter).

__global__ __launch_bounds__(512, 1) void lstm_step_kernel(
    const bf16_t* __restrict__ feat, const bf16_t* __restrict__ featT,
    const bf16_t* __restrict__ wcat2, const float* __restrict__ biasc,
    const bf16_t* __restrict__ hin, bf16_t* __restrict__ hout,
    bf16_t* __restrict__ cbuf, int s) {
  extern __shared__ __align__(16) char smem[];   // 2 x 32 KB A buffers

  const int t = threadIdx.x;
  const int l = t & 63, w = t >> 6;
  const int wr = w >> 2, wc = w & 3;   // 2M x 4N; wave tile 128 x 64
  const int lr = l & 15, lq = l >> 4;
  const int sx = lr & 7;
  const int srow = l >> 3;
  const int sslot = (l & 7) ^ (srow & 7);

  // grid 512 = 4 cell x 16 bm x 8 bn; XCD swizzle (bijective, 512 % 8 == 0)
  const int bid = blockIdx.x;
  const int widx = (bid & 7) * 64 + (bid >> 3);
  const int cell = widx >> 7;
  const int rwk = widx & 127;
  const int bm = rwk >> 3, bn = rwk & 7;

  const bf16_t* xsrc = (cell < 2) ? feat : featT;
  const int off = ((cell & 1) ? (63 - s) : s) * 64;
  const int mat = (cell < 2) ? cell : 2;
  const bf16_t* hc = hin + (size_t)cell * kB * kH;
  bf16_t* cc = cbuf + (size_t)cell * kB * kH;

  // A staging: 256 rows x 64 K per tile; 512 threads x 4 loads.
  auto stageA = [&](int kt, int buf) {
    bf16_t* base = (bf16_t*)(smem + buf * 32768);
#pragma unroll
    for (int j = 0; j < 4; ++j) {
      const int row0 = j * 64 + w * 8;          // wave-uniform
      bf16_t* dst = base + row0 * 64;
      const bf16_t* src = (kt == 0)
          ? xsrc + (size_t)(bm * 256 + row0 + srow) * kFS + off + sslot * 8
          : hc + (size_t)(bm * 256 + row0 + srow) * kH + (kt - 1) * 64 + sslot * 8;
      gload16(src, dst);
    }
  };

  // c-tile stage into buf1 (dead after tile 7): 256 rows x 64 units bf16, row-major 128B.
  auto stageC = [&]() {
#pragma unroll
    for (int q = 0; q < 4; ++q) {
      const int rowg = (w * 4 + q) * 8 + (l >> 3);             // per-lane global row
      bf16_t* dst = (bf16_t*)(smem + 32768) + (w * 4 + q) * 512;  // wave-uniform
      const bf16_t* src = cc + (size_t)(bm * 256 + rowg) * kH + bn * 64 + (l & 7) * 8;
      gload16(src, dst);
    }
  };

  // B fragment loads: chunk (mat, nb, kt, kk) at elem offset chunkIdx*512 + l*8.
  const size_t wb0 = ((size_t)mat * 128 + bn * 16 + wc * 4) * 9;
  auto loadB = [&](int kt, bfrag (&d)[8]) {
#pragma unroll
    for (int nn = 0; nn < 4; ++nn)
#pragma unroll
      for (int kk = 0; kk < 2; ++kk)
        d[nn * 2 + kk] = *reinterpret_cast<const bfrag*>(
            wcat2 + (((wb0 + (size_t)nn * 9 + kt) * 2 + kk) << 9) + l * 8);
  };

  f32x4 acc[8][4];
#pragma unroll
  for (int i = 0; i < 8; ++i)
#pragma unroll
    for (int j = 0; j < 4; ++j) acc[i][j] = (f32x4){0.f, 0.f, 0.f, 0.f};

  bfrag bA[8], bB[8];

  // prologue
  stageA(0, 0);
  loadB(0, bA);
  asm volatile("s_waitcnt vmcnt(0)" ::: "memory");
  __builtin_amdgcn_sched_barrier(0);
  __builtin_amdgcn_s_barrier();

#pragma unroll
  for (int kt = 0; kt < 9; ++kt) {
    const int cur = kt & 1;
    const bf16_t* As_ = (const bf16_t*)(smem + cur * 32768);
    bfrag (&bCur)[8] = (kt & 1) ? bB : bA;
    bfrag (&bNxt)[8] = (kt & 1) ? bA : bB;

    if (kt < 8) stageA(kt + 1, cur ^ 1);
    if (kt == 8) stageC();   // buf1 dead (tile 7 consumed); lands under tile-8 MFMA

    bfrag a[8];
    // ---- sub-burst 1: mi 0..3 ----
#pragma unroll
    for (int mi = 0; mi < 4; ++mi)
#pragma unroll
      for (int kk = 0; kk < 2; ++kk)
        a[mi * 2 + kk] = *reinterpret_cast<const bfrag*>(
            As_ + (wr * 128 + mi * 16 + lr) * 64 + (((kk * 4 + lq) ^ sx) * 8));
    __builtin_amdgcn_s_setprio(1);
#pragma unroll
    for (int kk = 0; kk < 2; ++kk)
#pragma unroll
      for (int mi = 0; mi < 4; ++mi)
#pragma unroll
        for (int nn = 0; nn < 4; ++nn)
          acc[mi][nn] = mfma16(a[mi * 2 + kk], bCur[nn * 2 + kk], acc[mi][nn]);
    __builtin_amdgcn_s_setprio(0);

    if (kt < 8) loadB(kt + 1, bNxt);   // lands under sub-burst 2 + barrier

    // ---- sub-burst 2: mi 4..7 ----
#pragma unroll
    for (int mi = 0; mi < 4; ++mi)
#pragma unroll
      for (int kk = 0; kk < 2; ++kk)
        a[mi * 2 + kk] = *reinterpret_cast<const bfrag*>(
            As_ + (wr * 128 + 64 + mi * 16 + lr) * 64 + (((kk * 4 + lq) ^ sx) * 8));
    __builtin_amdgcn_s_setprio(1);
#pragma unroll
    for (int kk = 0; kk < 2; ++kk)
#pragma unroll
      for (int mi = 0; mi < 4; ++mi)
#pragma unroll
        for (int nn = 0; nn < 4; ++nn)
          acc[4 + mi][nn] = mfma16(a[mi * 2 + kk], bCur[nn * 2 + kk], acc[4 + mi][nn]);
    __builtin_amdgcn_s_setprio(0);
    __builtin_amdgcn_sched_barrier(0);

    if (kt < 8) {
      asm volatile("s_waitcnt vmcnt(8)" ::: "memory");  // A-stage landed; 8 b-loads in flight
      __builtin_amdgcn_sched_barrier(0);
      __builtin_amdgcn_s_barrier();
    }
  }

  // drain c-stage + all frag reads; all waves past their buf0/buf1 reads
  asm volatile("s_waitcnt vmcnt(0) lgkmcnt(0)" ::: "memory");
  __builtin_amdgcn_sched_barrier(0);
  __builtin_amdgcn_s_barrier();

  // ---- epilogue: gates from LDS c-tile; write c (in place, buf1) + h (buf0) ----
  char* cl = smem + 32768;   // c tile [256][64] bf16
  char* hl = smem;           // h tile [256][64] bf16
  const float* biasn = biasc + mat * kNG + bn * 256 + wc * 64;
  const float bb0 = biasn[0 * 16 + lr];
  const float bb1 = biasn[1 * 16 + lr];
  const float bb2 = biasn[2 * 16 + lr];
  const float bb3 = biasn[3 * 16 + lr];
  const int ucol2 = (wc * 16 + lr) * 2;   // byte offset of unit col within 128B row
#pragma unroll
  for (int mi = 0; mi < 8; ++mi) {
#pragma unroll
    for (int j = 0; j < 4; ++j) {
      const int row = wr * 128 + mi * 16 + lq * 4 + j;
      const int boff = row * 128 + ucol2;
      const float cold = (float)*reinterpret_cast<const bf16_t*>(cl + boff);
      const float iv = sigf(acc[mi][0][j] + bb0);
      const float fv = sigf(acc[mi][1][j] + bb1);
      const float gv = tanh_fast(acc[mi][2][j] + bb2);
      const float ov = sigf(acc[mi][3][j] + bb3);
      const float cn = fv * cold + iv * gv;
      *reinterpret_cast<bf16_t*>(cl + boff) = (bf16_t)cn;
      *reinterpret_cast<bf16_t*>(hl + boff) = (bf16_t)(ov * tanh_fast(cn));
    }
  }
  __syncthreads();

  // ---- copy-out: 8 consecutive lanes cover one row's 128 B (full coalescing) ----
  bf16_t* hdst = hout + (size_t)cell * kB * kH;
  const size_t gbase = (size_t)(bm * 256) * kH + bn * 64;
#pragma unroll
  for (int q = 0; q < 4; ++q) {
    const int i2 = q * 512 + t;
    const int row = i2 >> 3, ch = i2 & 7;
    const size_t ge = gbase + (size_t)row * kH + ch * 8;
    const bfrag cv = *reinterpret_cast<const bfrag*>(cl + row * 128 + ch * 16);
    const bfrag hv = *reinterpret_cast<const bfrag*>(hl + row * 128 + ch * 16);
    __builtin_nontemporal_store(cv, reinterpret_cast<bfrag*>(cc + ge));
    *reinterpret_cast<bfrag*>(hdst + ge) = hv;
  }
}

// ---------------- head: wave shuffle reduce ----------------

__global__ __launch_bounds__(256) void head_kernel(const bf16_t* __restrict__ hfin,
                                                   const float* __restrict__ W3,
                                                   const float* __restrict__ b3,
                                                   float* __restrict__ out) {
  const int b = blockIdx.x, t = threadIdx.x;
  const int l = t & 63, w = t >> 6;
  float acc[10];
#pragma unroll
  for (int j = 0; j < 10; ++j) acc[j] = 0.f;
  for (int k = t; k < 2048; k += 256) {
    const int cell = k >> 9, u = k & 511;
    const float hv = (float)hfin[((size_t)cell * kB + b) * kH + u];
#pragma unroll
    for (int j = 0; j < 10; ++j) acc[j] += hv * W3[j * 2048 + k];
  }
#pragma unroll
  for (int j = 0; j < 10; ++j)
#pragma unroll
    for (int o = 32; o > 0; o >>= 1) acc[j] += __shfl_down(acc[j], o, 64);
  __shared__ float wred[4][10];
  if (l == 0)
#pragma unroll
    for (int j = 0; j < 10; ++j) wred[w][j] = acc[j];
  __syncthreads();
  if (t == 0) {
    float logits[10];
#pragma unroll
    for (int j = 0; j < 10; ++j)
      logits[j] = wred[0][j] + wred[1][j] + wred[2][j] + wred[3][j] + b3[j];
    float mx = logits[0];
#pragma unroll
    for (int j = 1; j < 10; ++j) mx = fmaxf(mx, logits[j]);
    float se = 0.f;
#pragma unroll
    for (int j = 0; j < 10; ++j) se += expf(logits[j] - mx);
    const float lse = mx + logf(se);
#pragma unroll
    for (int j = 0; j < 10; ++j) out[(size_t)b * 10 + j] = logits[j] - lse;
  }
}

}  // namespace

extern "C" void kernel_launch(void* const* d_in, const int* in_sizes, int n_in,
                              void* d_out, int out_size, void* d_ws, size_t ws_size,
                              hipStream_t stream) {
  const float* x     = (const float*)d_in[0];
  const float* h0    = (const float*)d_in[1];
  const float* c0    = (const float*)d_in[2];
  const float* W1    = (const float*)d_in[3];
  const float* b1    = (const float*)d_in[4];
  const float* Wih_l = (const float*)d_in[5];
  const float* Whh_l = (const float*)d_in[6];
  const float* bih_l = (const float*)d_in[7];
  const float* bhh_l = (const float*)d_in[8];
  const float* Wih_r = (const float*)d_in[9];
  const float* Whh_r = (const float*)d_in[10];
  const float* bih_r = (const float*)d_in[11];
  const float* bhh_r = (const float*)d_in[12];
  const float* Wih_d = (const float*)d_in[13];
  const float* Whh_d = (const float*)d_in[14];
  const float* bih_d = (const float*)d_in[15];
  const float* bhh_d = (const float*)d_in[16];
  const float* W3    = (const float*)d_in[17];
  const float* b3    = (const float*)d_in[18];
  float* out = (float*)d_out;

  char* p = (char*)d_ws;
  auto take = [&](size_t bytes) {
    char* r = p;
    p += (bytes + 255) & ~(size_t)255;
    return r;
  };
  bf16_t* xb    = (bf16_t*)take((size_t)kB * kIN * 2);   // later reused as featT
  bf16_t* w1b   = (bf16_t*)take((size_t)kFS * kIN * 2);  // later reused as hbuf (2 slots)
  bf16_t* feat  = (bf16_t*)take((size_t)kB * kFS * 2);
  bf16_t* wcat2 = (bf16_t*)take((size_t)3 * 128 * 9 * 2 * 64 * 8 * 2);
  float*  biasc = (float*)take((size_t)3 * kNG * 4);
  bf16_t* cbuf  = (bf16_t*)take((size_t)4 * kB * kH * 2);
  bf16_t* featT = xb;   // safe: gemm_feat (reads xb) precedes transpose (writes featT)
  bf16_t* hbuf  = w1b;  // safe: gemm_feat (reads w1b) precedes pack_hc
  const size_t HSZ = (size_t)4 * kB * kH;

  (void)hipFuncSetAttribute(reinterpret_cast<const void*>(&lstm_step_kernel),
                            hipFuncAttributeMaxDynamicSharedMemorySize, 65536);

  f2b4_kernel<<<(kB * kIN / 4) / 256, 256, 0, stream>>>(x, xb, kB * kIN / 4);
  f2b4_kernel<<<(kFS * kIN / 4) / 256, 256, 0, stream>>>(W1, w1b, kFS * kIN / 4);
  gemm_feat_kernel<<<dim3(1024), 256, 0, stream>>>(xb, w1b, b1, feat);
  transpose64_kernel<<<kB, 256, 0, stream>>>(feat, featT);
  {
    const int total = 3 * 128 * 9 * 2 * 64 * 8;
    pack_wcat2_kernel<<<(total + 255) / 256, 256, 0, stream>>>(
        Wih_l, Whh_l, Wih_r, Whh_r, Wih_d, Whh_d, wcat2);
  }
  pack_bias_kernel<<<(3 * kNG + 255) / 256, 256, 0, stream>>>(
      bih_l, bhh_l, bih_r, bhh_r, bih_d, bhh_d, biasc);
  pack_hc_kernel<<<(int)(HSZ / 256), 256, 0, stream>>>(h0, c0, hbuf, cbuf, (int)HSZ);

  for (int s = 0; s < 64; ++s) {
    lstm_step_kernel<<<dim3(512), 512, 65536, stream>>>(
        feat, featT, wcat2, biasc,
        hbuf + (size_t)(s & 1) * HSZ, hbuf + (size_t)((s + 1) & 1) * HSZ, cbuf, s);
  }
  head_kernel<<<kB, 256, 0, stream>>>(hbuf, W3, b3, out);
}

// Round 15
// 3861.662 us; speedup vs baseline: 5.6668x; 1.1046x over previous
//
#include <hip/hip_runtime.h>
#include <cstddef>
#include <cstdint>

namespace {

constexpr int kB  = 4096;   // batch
constexpr int kIN = 4096;
constexpr int kFS = 4096;
constexpr int kS  = 64;
constexpr int kH  = 512;
constexpr int kNG = 2048;   // 4*H
constexpr int kKC = 576;    // 64 (input slice) + 512 (hidden)

typedef __bf16 bf16_t;
typedef __bf16 bfrag  __attribute__((ext_vector_type(8)));
typedef __bf16 bf16v4 __attribute__((ext_vector_type(4)));
typedef float  f32x4  __attribute__((ext_vector_type(4)));

__device__ __forceinline__ void gload16(const void* g, void* l) {
  __builtin_amdgcn_global_load_lds(
      (const __attribute__((address_space(1))) void*)g,
      (__attribute__((address_space(3))) void*)l, 16, 0, 0);
}

__device__ __forceinline__ float sigf(float x) { return 1.0f / (1.0f + __expf(-x)); }
__device__ __forceinline__ float tanh_fast(float x) {
  float e = __expf(2.0f * x);
  return 1.0f - 2.0f / (e + 1.0f);
}

__device__ __forceinline__ f32x4 mfma16(bfrag a, bfrag b, f32x4 c) {
  return __builtin_amdgcn_mfma_f32_16x16x32_bf16(a, b, c, 0, 0, 0);
}

// ---------------- pack kernels ----------------

__global__ __launch_bounds__(256) void f2b4_kernel(const float* __restrict__ in,
                                                   bf16_t* __restrict__ out, int n4) {
  int i = blockIdx.x * 256 + threadIdx.x;
  if (i >= n4) return;
  float4 v = reinterpret_cast<const float4*>(in)[i];
  bf16v4 o = {(bf16_t)v.x, (bf16_t)v.y, (bf16_t)v.z, (bf16_t)v.w};
  *reinterpret_cast<bf16v4*>(out + (size_t)i * 4) = o;
}

// W1 -> MFMA-fragment-order pack (plain cols, no gate interleave).
// chunk (nb, kt, kk) = 64 lanes x 8 bf16; lane l: col = nb*16+(l&15),
// k = kt*64 + kk*32 + (l>>4)*8.  nb 0..255, kt 0..63, kk 0..1.
__global__ __launch_bounds__(256) void pack_w1frag_kernel(const float* __restrict__ W1,
                                                          bf16_t* __restrict__ w1f) {
  int idx = blockIdx.x * 256 + threadIdx.x;   // total = 4096*4096 = 16.8M
  int e  = idx & 7;
  int l  = (idx >> 3) & 63;
  int kk = (idx >> 9) & 1;
  int r  = idx >> 10;
  int kt = r & 63;
  int nb = r >> 6;
  const int col = nb * 16 + (l & 15);
  const int k = kt * 64 + kk * 32 + (l >> 4) * 8 + e;
  w1f[idx] = (bf16_t)W1[(size_t)col * kIN + k];
}

// wcat2: MFMA-fragment-order weight pack (verified R9).
__global__ __launch_bounds__(256) void pack_wcat2_kernel(
    const float* __restrict__ Wih_l, const float* __restrict__ Whh_l,
    const float* __restrict__ Wih_r, const float* __restrict__ Whh_r,
    const float* __restrict__ Wih_d, const float* __restrict__ Whh_d,
    bf16_t* __restrict__ wcat2) {
  const int total = 3 * 128 * 9 * 2 * 64 * 8;
  int idx = blockIdx.x * 256 + threadIdx.x;
  if (idx >= total) return;
  int e  = idx & 7;
  int l  = (idx >> 3) & 63;
  int kk = (idx >> 9) & 1;
  int r  = idx >> 10;
  int kt = r % 9;
  int matnb = r / 9;
  int mat = matnb >> 7;
  int nb  = matnb & 127;
  const int c = nb * 16 + (l & 15);
  const int g = (c >> 4) & 3;
  const int u = (c >> 6) * 16 + (c & 15);
  const int orow = g * kH + u;
  const int k = kt * 64 + kk * 32 + (l >> 4) * 8 + e;
  const float* Wih = (mat == 0) ? Wih_l : (mat == 1) ? Wih_r : Wih_d;
  const float* Whh = (mat == 0) ? Whh_l : (mat == 1) ? Whh_r : Whh_d;
  float v = (k < 64) ? Wih[(size_t)orow * 64 + k] : Whh[(size_t)orow * 512 + (k - 64)];
  wcat2[idx] = (bf16_t)v;
}

__global__ __launch_bounds__(256) void pack_bias_kernel(
    const float* __restrict__ bih_l, const float* __restrict__ bhh_l,
    const float* __restrict__ bih_r, const float* __restrict__ bhh_r,
    const float* __restrict__ bih_d, const float* __restrict__ bhh_d,
    float* __restrict__ biasc) {
  int idx = blockIdx.x * 256 + threadIdx.x;
  if (idx >= 3 * kNG) return;
  int mat = idx / kNG;
  int c = idx - mat * kNG;
  int g = (c >> 4) & 3;
  int u = (c >> 6) * 16 + (c & 15);
  int orow = g * kH + u;
  const float* bi = (mat == 0) ? bih_l : (mat == 1) ? bih_r : bih_d;
  const float* bh = (mat == 0) ? bhh_l : (mat == 1) ? bhh_r : bhh_d;
  biasc[idx] = bi[orow] + bh[orow];
}

__global__ __launch_bounds__(256) void pack_hc_kernel(const float* __restrict__ h0,
                                                      const float* __restrict__ c0,
                                                      bf16_t* __restrict__ hbuf0,
                                                      float* __restrict__ cbuf, int n) {
  int i = blockIdx.x * 256 + threadIdx.x;
  if (i >= n) return;
  hbuf0[i] = (bf16_t)h0[i];
  cbuf[i]  = c0[i];
}

__global__ __launch_bounds__(256) void transpose64_kernel(const bf16_t* __restrict__ feat,
                                                          bf16_t* __restrict__ featT) {
  __shared__ bf16_t tile[64][65];
  const int b = blockIdx.x;
  const bf16_t* src = feat + (size_t)b * kFS;
  bf16_t* dst = featT + (size_t)b * kFS;
  for (int i = threadIdx.x; i < 4096; i += 256) tile[i >> 6][i & 63] = src[i];
  __syncthreads();
  for (int i = threadIdx.x; i < 4096; i += 256) dst[i] = tile[i & 63][i >> 6];
}

// ---------------- feat GEMM: 256x256, 8 waves, A-LDS dbuf BK=64, B-direct ----------------
// Port of the R9 step K-loop (session-verified schedule) to the K=4096 GEMM:
// A (=x bf16) staged via global_load_lds into a 2x32KB double buffer with T2 swizzle;
// B fragments loaded straight from fragment-ordered w1f (ping-pong regs, unroll-2 for
// static indices). One raw s_barrier per K-tile; vmcnt(8) covers only the A stage.

__global__ __launch_bounds__(512, 1) void gemm_feat256_kernel(
    const bf16_t* __restrict__ X, const bf16_t* __restrict__ w1f,
    const float* __restrict__ b1, bf16_t* __restrict__ feat) {
  extern __shared__ __align__(16) char smem[];   // 2 x 32 KB A buffers

  const int t = threadIdx.x;
  const int l = t & 63, w = t >> 6;
  const int wr = w >> 2, wc = w & 3;   // 2M x 4N; wave tile 128 x 64
  const int lr = l & 15, lq = l >> 4;
  const int sx = lr & 7;
  const int srow = l >> 3;
  const int sslot = (l & 7) ^ (srow & 7);

  // grid 256 = 16 bn x 16 bm; XCD swizzle: consecutive widx = 2 bn panels x 16 bm,
  // so each XCD's B working set is 2 panels (4.2 MB ~ L2) shared by 16 bm blocks.
  const int bid = blockIdx.x;
  const int widx = (bid & 7) * 32 + (bid >> 3);
  const int bn = widx >> 4, bm = widx & 15;

  auto stageA = [&](int kt, int buf) {
    bf16_t* base = (bf16_t*)(smem + buf * 32768);
#pragma unroll
    for (int j = 0; j < 4; ++j) {
      const int row0 = j * 64 + w * 8;          // wave-uniform
      bf16_t* dst = base + row0 * 64;
      const bf16_t* src =
          X + (size_t)(bm * 256 + row0 + srow) * kIN + kt * 64 + sslot * 8;
      gload16(src, dst);
    }
  };

  auto loadB = [&](int kt, bfrag (&d)[8]) {
#pragma unroll
    for (int nn = 0; nn < 4; ++nn) {
      const int nb = bn * 16 + wc * 4 + nn;
#pragma unroll
      for (int kk = 0; kk < 2; ++kk)
        d[nn * 2 + kk] = *reinterpret_cast<const bfrag*>(
            w1f + ((((size_t)nb * 64 + kt) * 2 + kk) << 9) + l * 8);
    }
  };

  f32x4 acc[8][4];
#pragma unroll
  for (int i = 0; i < 8; ++i)
#pragma unroll
    for (int j = 0; j < 4; ++j) acc[i][j] = (f32x4){0.f, 0.f, 0.f, 0.f};

  bfrag bA[8], bB[8];

  // prologue
  stageA(0, 0);
  loadB(0, bA);
  asm volatile("s_waitcnt vmcnt(0)" ::: "memory");
  __builtin_amdgcn_sched_barrier(0);
  __builtin_amdgcn_s_barrier();

  auto tileBody = [&](int kt, int cur, bfrag (&bCur)[8], bfrag (&bNxt)[8], bool last) {
    const bf16_t* As_ = (const bf16_t*)(smem + cur * 32768);
    if (!last) stageA(kt + 1, cur ^ 1);
    bfrag a[8];
#pragma unroll
    for (int mi = 0; mi < 4; ++mi)
#pragma unroll
      for (int kk = 0; kk < 2; ++kk)
        a[mi * 2 + kk] = *reinterpret_cast<const bfrag*>(
            As_ + (wr * 128 + mi * 16 + lr) * 64 + (((kk * 4 + lq) ^ sx) * 8));
    __builtin_amdgcn_s_setprio(1);
#pragma unroll
    for (int kk = 0; kk < 2; ++kk)
#pragma unroll
      for (int mi = 0; mi < 4; ++mi)
#pragma unroll
        for (int nn = 0; nn < 4; ++nn)
          acc[mi][nn] = mfma16(a[mi * 2 + kk], bCur[nn * 2 + kk], acc[mi][nn]);
    __builtin_amdgcn_s_setprio(0);
    if (!last) loadB(kt + 1, bNxt);
#pragma unroll
    for (int mi = 0; mi < 4; ++mi)
#pragma unroll
      for (int kk = 0; kk < 2; ++kk)
        a[mi * 2 + kk] = *reinterpret_cast<const bfrag*>(
            As_ + (wr * 128 + 64 + mi * 16 + lr) * 64 + (((kk * 4 + lq) ^ sx) * 8));
    __builtin_amdgcn_s_setprio(1);
#pragma unroll
    for (int kk = 0; kk < 2; ++kk)
#pragma unroll
      for (int mi = 0; mi < 4; ++mi)
#pragma unroll
        for (int nn = 0; nn < 4; ++nn)
          acc[4 + mi][nn] = mfma16(a[mi * 2 + kk], bCur[nn * 2 + kk], acc[4 + mi][nn]);
    __builtin_amdgcn_s_setprio(0);
    __builtin_amdgcn_sched_barrier(0);
    if (!last) {
      asm volatile("s_waitcnt vmcnt(8)" ::: "memory");  // A stage landed; b-loads in flight
      __builtin_amdgcn_sched_barrier(0);
      __builtin_amdgcn_s_barrier();
    }
  };

#pragma unroll 1
  for (int kt2 = 0; kt2 < 32; ++kt2) {
    tileBody(2 * kt2, 0, bA, bB, false);
    tileBody(2 * kt2 + 1, 1, bB, bA, kt2 == 31);
  }

  // epilogue: bias + relu, scatter store (same mapping family as step epilogue)
  const int row0 = bm * 256 + wr * 128 + lq * 4;
  float bb[4];
#pragma unroll
  for (int nn = 0; nn < 4; ++nn)
    bb[nn] = b1[bn * 256 + (wc * 4 + nn) * 16 + lr];
#pragma unroll
  for (int mi = 0; mi < 8; ++mi) {
#pragma unroll
    for (int nn = 0; nn < 4; ++nn) {
      const int col = bn * 256 + (wc * 4 + nn) * 16 + lr;
#pragma unroll
      for (int j = 0; j < 4; ++j) {
        const int row = row0 + mi * 16 + j;
        feat[(size_t)row * kFS + col] = (bf16_t)fmaxf(acc[mi][nn][j] + bb[nn], 0.0f);
      }
    }
  }
}

// ---------------- step kernel (R9 exact: best verified, fp32 c, no NT) ----------------

__global__ __launch_bounds__(512, 1) void lstm_step_kernel(
    const bf16_t* __restrict__ feat, const bf16_t* __restrict__ featT,
    const bf16_t* __restrict__ wcat2, const float* __restrict__ biasc,
    const bf16_t* __restrict__ hin, bf16_t* __restrict__ hout,
    float* __restrict__ cbuf, int s) {
  extern __shared__ __align__(16) char smem[];   // 2 x 32 KB A buffers

  const int t = threadIdx.x;
  const int l = t & 63, w = t >> 6;
  const int wr = w >> 2, wc = w & 3;   // 2M x 4N; wave tile 128 x 64
  const int lr = l & 15, lq = l >> 4;
  const int sx = lr & 7;
  const int srow = l >> 3;
  const int sslot = (l & 7) ^ (srow & 7);

  // grid 512 = 4 cell x 16 bm x 8 bn; XCD swizzle (bijective, 512 % 8 == 0)
  const int bid = blockIdx.x;
  const int widx = (bid & 7) * 64 + (bid >> 3);
  const int cell = widx >> 7;
  const int rwk = widx & 127;
  const int bm = rwk >> 3, bn = rwk & 7;

  const bf16_t* xsrc = (cell < 2) ? feat : featT;
  const int off = ((cell & 1) ? (63 - s) : s) * 64;
  const int mat = (cell < 2) ? cell : 2;
  const bf16_t* hc = hin + (size_t)cell * kB * kH;

  auto stageA = [&](int kt, int buf) {
    bf16_t* base = (bf16_t*)(smem + buf * 32768);
#pragma unroll
    for (int j = 0; j < 4; ++j) {
      const int row0 = j * 64 + w * 8;          // wave-uniform
      bf16_t* dst = base + row0 * 64;
      const bf16_t* src = (kt == 0)
          ? xsrc + (size_t)(bm * 256 + row0 + srow) * kFS + off + sslot * 8
          : hc + (size_t)(bm * 256 + row0 + srow) * kH + (kt - 1) * 64 + sslot * 8;
      gload16(src, dst);
    }
  };

  const size_t wb0 = ((size_t)mat * 128 + bn * 16 + wc * 4) * 9;
  auto loadB = [&](int kt, bfrag (&d)[8]) {
#pragma unroll
    for (int nn = 0; nn < 4; ++nn)
#pragma unroll
      for (int kk = 0; kk < 2; ++kk)
        d[nn * 2 + kk] = *reinterpret_cast<const bfrag*>(
            wcat2 + (((wb0 + (size_t)nn * 9 + kt) * 2 + kk) << 9) + l * 8);
  };

  f32x4 acc[8][4];
#pragma unroll
  for (int i = 0; i < 8; ++i)
#pragma unroll
    for (int j = 0; j < 4; ++j) acc[i][j] = (f32x4){0.f, 0.f, 0.f, 0.f};

  bfrag bA[8], bB[8];

  // prologue
  stageA(0, 0);
  loadB(0, bA);
  asm volatile("s_waitcnt vmcnt(0)" ::: "memory");
  __builtin_amdgcn_sched_barrier(0);
  __builtin_amdgcn_s_barrier();

#pragma unroll
  for (int kt = 0; kt < 9; ++kt) {
    const int cur = kt & 1;
    const bf16_t* As_ = (const bf16_t*)(smem + cur * 32768);
    bfrag (&bCur)[8] = (kt & 1) ? bB : bA;
    bfrag (&bNxt)[8] = (kt & 1) ? bA : bB;

    if (kt < 8) stageA(kt + 1, cur ^ 1);

    bfrag a[8];
#pragma unroll
    for (int mi = 0; mi < 4; ++mi)
#pragma unroll
      for (int kk = 0; kk < 2; ++kk)
        a[mi * 2 + kk] = *reinterpret_cast<const bfrag*>(
            As_ + (wr * 128 + mi * 16 + lr) * 64 + (((kk * 4 + lq) ^ sx) * 8));
    __builtin_amdgcn_s_setprio(1);
#pragma unroll
    for (int kk = 0; kk < 2; ++kk)
#pragma unroll
      for (int mi = 0; mi < 4; ++mi)
#pragma unroll
        for (int nn = 0; nn < 4; ++nn)
          acc[mi][nn] = mfma16(a[mi * 2 + kk], bCur[nn * 2 + kk], acc[mi][nn]);
    __builtin_amdgcn_s_setprio(0);

    if (kt < 8) loadB(kt + 1, bNxt);

#pragma unroll
    for (int mi = 0; mi < 4; ++mi)
#pragma unroll
      for (int kk = 0; kk < 2; ++kk)
        a[mi * 2 + kk] = *reinterpret_cast<const bfrag*>(
            As_ + (wr * 128 + 64 + mi * 16 + lr) * 64 + (((kk * 4 + lq) ^ sx) * 8));
    __builtin_amdgcn_s_setprio(1);
#pragma unroll
    for (int kk = 0; kk < 2; ++kk)
#pragma unroll
      for (int mi = 0; mi < 4; ++mi)
#pragma unroll
        for (int nn = 0; nn < 4; ++nn)
          acc[4 + mi][nn] = mfma16(a[mi * 2 + kk], bCur[nn * 2 + kk], acc[4 + mi][nn]);
    __builtin_amdgcn_s_setprio(0);
    __builtin_amdgcn_sched_barrier(0);

    if (kt < 8) {
      asm volatile("s_waitcnt vmcnt(8)" ::: "memory");
      __builtin_amdgcn_sched_barrier(0);
      __builtin_amdgcn_s_barrier();
    }
  }

  // epilogue: per-lane gate fusion (no LDS, no barriers)
  const float* biasn = biasc + mat * kNG + bn * 256 + wc * 64;
  const float bb0 = biasn[0 * 16 + lr];
  const float bb1 = biasn[1 * 16 + lr];
  const float bb2 = biasn[2 * 16 + lr];
  const float bb3 = biasn[3 * 16 + lr];
  const int u = (bn * 4 + wc) * 16 + lr;
  const int row0 = bm * 256 + wr * 128 + lq * 4;
#pragma unroll
  for (int mi = 0; mi < 8; ++mi) {
#pragma unroll
    for (int j = 0; j < 4; ++j) {
      const float iv = sigf(acc[mi][0][j] + bb0);
      const float fv = sigf(acc[mi][1][j] + bb1);
      const float gv = tanh_fast(acc[mi][2][j] + bb2);
      const float ov = sigf(acc[mi][3][j] + bb3);
      const int row = row0 + mi * 16 + j;
      const size_t cidx = ((size_t)cell * kB + row) * kH + u;
      const float cn = fv * cbuf[cidx] + iv * gv;
      cbuf[cidx] = cn;
      hout[cidx] = (bf16_t)(ov * tanh_fast(cn));
    }
  }
}

// ---------------- head: wave shuffle reduce ----------------

__global__ __launch_bounds__(256) void head_kernel(const bf16_t* __restrict__ hfin,
                                                   const float* __restrict__ W3,
                                                   const float* __restrict__ b3,
                                                   float* __restrict__ out) {
  const int b = blockIdx.x, t = threadIdx.x;
  const int l = t & 63, w = t >> 6;
  float acc[10];
#pragma unroll
  for (int j = 0; j < 10; ++j) acc[j] = 0.f;
  for (int k = t; k < 2048; k += 256) {
    const int cell = k >> 9, u = k & 511;
    const float hv = (float)hfin[((size_t)cell * kB + b) * kH + u];
#pragma unroll
    for (int j = 0; j < 10; ++j) acc[j] += hv * W3[j * 2048 + k];
  }
#pragma unroll
  for (int j = 0; j < 10; ++j)
#pragma unroll
    for (int o = 32; o > 0; o >>= 1) acc[j] += __shfl_down(acc[j], o, 64);
  __shared__ float wred[4][10];
  if (l == 0)
#pragma unroll
    for (int j = 0; j < 10; ++j) wred[w][j] = acc[j];
  __syncthreads();
  if (t == 0) {
    float logits[10];
#pragma unroll
    for (int j = 0; j < 10; ++j)
      logits[j] = wred[0][j] + wred[1][j] + wred[2][j] + wred[3][j] + b3[j];
    float mx = logits[0];
#pragma unroll
    for (int j = 1; j < 10; ++j) mx = fmaxf(mx, logits[j]);
    float se = 0.f;
#pragma unroll
    for (int j = 0; j < 10; ++j) se += expf(logits[j] - mx);
    const float lse = mx + logf(se);
#pragma unroll
    for (int j = 0; j < 10; ++j) out[(size_t)b * 10 + j] = logits[j] - lse;
  }
}

}  // namespace

extern "C" void kernel_launch(void* const* d_in, const int* in_sizes, int n_in,
                              void* d_out, int out_size, void* d_ws, size_t ws_size,
                              hipStream_t stream) {
  const float* x     = (const float*)d_in[0];
  const float* h0    = (const float*)d_in[1];
  const float* c0    = (const float*)d_in[2];
  const float* W1    = (const float*)d_in[3];
  const float* b1    = (const float*)d_in[4];
  const float* Wih_l = (const float*)d_in[5];
  const float* Whh_l = (const float*)d_in[6];
  const float* bih_l = (const float*)d_in[7];
  const float* bhh_l = (const float*)d_in[8];
  const float* Wih_r = (const float*)d_in[9];
  const float* Whh_r = (const float*)d_in[10];
  const float* bih_r = (const float*)d_in[11];
  const float* bhh_r = (const float*)d_in[12];
  const float* Wih_d = (const float*)d_in[13];
  const float* Whh_d = (const float*)d_in[14];
  const float* bih_d = (const float*)d_in[15];
  const float* bhh_d = (const float*)d_in[16];
  const float* W3    = (const float*)d_in[17];
  const float* b3    = (const float*)d_in[18];
  float* out = (float*)d_out;

  char* p = (char*)d_ws;
  auto take = [&](size_t bytes) {
    char* r = p;
    p += (bytes + 255) & ~(size_t)255;
    return r;
  };
  bf16_t* xb    = (bf16_t*)take((size_t)kB * kIN * 2);   // later reused as featT
  bf16_t* w1f   = (bf16_t*)take((size_t)kFS * kIN * 2);  // later reused as hbuf (2 slots)
  bf16_t* feat  = (bf16_t*)take((size_t)kB * kFS * 2);
  bf16_t* wcat2 = (bf16_t*)take((size_t)3 * 128 * 9 * 2 * 64 * 8 * 2);
  float*  biasc = (float*)take((size_t)3 * kNG * 4);
  float*  cbuf  = (float*)take((size_t)4 * kB * kH * 4);
  bf16_t* featT = xb;   // safe: gemm_feat (reads xb) precedes transpose (writes featT)
  bf16_t* hbuf  = w1f;  // safe: gemm_feat (reads w1f) precedes pack_hc
  const size_t HSZ = (size_t)4 * kB * kH;

  (void)hipFuncSetAttribute(reinterpret_cast<const void*>(&lstm_step_kernel),
                            hipFuncAttributeMaxDynamicSharedMemorySize, 65536);
  (void)hipFuncSetAttribute(reinterpret_cast<const void*>(&gemm_feat256_kernel),
                            hipFuncAttributeMaxDynamicSharedMemorySize, 65536);

  f2b4_kernel<<<(kB * kIN / 4) / 256, 256, 0, stream>>>(x, xb, kB * kIN / 4);
  pack_w1frag_kernel<<<(kFS * kIN) / 256, 256, 0, stream>>>(W1, w1f);
  gemm_feat256_kernel<<<dim3(256), 512, 65536, stream>>>(xb, w1f, b1, feat);
  transpose64_kernel<<<kB, 256, 0, stream>>>(feat, featT);
  {
    const int total = 3 * 128 * 9 * 2 * 64 * 8;
    pack_wcat2_kernel<<<(total + 255) / 256, 256, 0, stream>>>(
        Wih_l, Whh_l, Wih_r, Whh_r, Wih_d, Whh_d, wcat2);
  }
  pack_bias_kernel<<<(3 * kNG + 255) / 256, 256, 0, stream>>>(
      bih_l, bhh_l, bih_r, bhh_r, bih_d, bhh_d, biasc);
  pack_hc_kernel<<<(int)(HSZ / 256), 256, 0, stream>>>(h0, c0, hbuf, cbuf, (int)HSZ);

  for (int s = 0; s < 64; ++s) {
    lstm_step_kernel<<<dim3(512), 512, 65536, stream>>>(
        feat, featT, wcat2, biasc,
        hbuf + (size_t)(s & 1) * HSZ, hbuf + (size_t)((s + 1) & 1) * HSZ, cbuf, s);
  }
  head_kernel<<<kB, 256, 0, stream>>>(hbuf, W3, b3, out);
}

// Round 16
// 3826.749 us; speedup vs baseline: 5.7185x; 1.0091x over previous
//
#include <hip/hip_runtime.h>
#include <cstddef>
#include <cstdint>

namespace {

constexpr int kB  = 4096;   // batch
constexpr int kIN = 4096;
constexpr int kFS = 4096;
constexpr int kS  = 64;
constexpr int kH  = 512;
constexpr int kNG = 2048;   // 4*H
constexpr int kKC = 576;    // 64 (input slice) + 512 (hidden)

typedef __bf16 bf16_t;
typedef __bf16 bfrag  __attribute__((ext_vector_type(8)));
typedef __bf16 bf16v4 __attribute__((ext_vector_type(4)));
typedef float  f32x4  __attribute__((ext_vector_type(4)));

__device__ __forceinline__ void gload16(const void* g, void* l) {
  __builtin_amdgcn_global_load_lds(
      (const __attribute__((address_space(1))) void*)g,
      (__attribute__((address_space(3))) void*)l, 16, 0, 0);
}

__device__ __forceinline__ float sigf(float x) { return 1.0f / (1.0f + __expf(-x)); }
__device__ __forceinline__ float tanh_fast(float x) {
  float e = __expf(2.0f * x);
  return 1.0f - 2.0f / (e + 1.0f);
}

__device__ __forceinline__ f32x4 mfma16(bfrag a, bfrag b, f32x4 c) {
  return __builtin_amdgcn_mfma_f32_16x16x32_bf16(a, b, c, 0, 0, 0);
}

// ---------------- pack kernels ----------------

__global__ __launch_bounds__(256) void f2b4_kernel(const float* __restrict__ in,
                                                   bf16_t* __restrict__ out, int n4) {
  int i = blockIdx.x * 256 + threadIdx.x;
  if (i >= n4) return;
  float4 v = reinterpret_cast<const float4*>(in)[i];
  bf16v4 o = {(bf16_t)v.x, (bf16_t)v.y, (bf16_t)v.z, (bf16_t)v.w};
  *reinterpret_cast<bf16v4*>(out + (size_t)i * 4) = o;
}

// wcat2: MFMA-fragment-order weight pack (verified R9).
// chunk (mat, nb, kt, kk) = 64 lanes x 8 bf16; lane l: col = nb*16+(l&15),
// k = kt*64 + kk*32 + (l>>4)*8. col c -> gate=(c>>4)&3, unit=(c>>6)*16+(c&15).
__global__ __launch_bounds__(256) void pack_wcat2_kernel(
    const float* __restrict__ Wih_l, const float* __restrict__ Whh_l,
    const float* __restrict__ Wih_r, const float* __restrict__ Whh_r,
    const float* __restrict__ Wih_d, const float* __restrict__ Whh_d,
    bf16_t* __restrict__ wcat2) {
  const int total = 3 * 128 * 9 * 2 * 64 * 8;
  int idx = blockIdx.x * 256 + threadIdx.x;
  if (idx >= total) return;
  int e  = idx & 7;
  int l  = (idx >> 3) & 63;
  int kk = (idx >> 9) & 1;
  int r  = idx >> 10;
  int kt = r % 9;
  int matnb = r / 9;
  int mat = matnb >> 7;
  int nb  = matnb & 127;
  const int c = nb * 16 + (l & 15);
  const int g = (c >> 4) & 3;
  const int u = (c >> 6) * 16 + (c & 15);
  const int orow = g * kH + u;
  const int k = kt * 64 + kk * 32 + (l >> 4) * 8 + e;
  const float* Wih = (mat == 0) ? Wih_l : (mat == 1) ? Wih_r : Wih_d;
  const float* Whh = (mat == 0) ? Whh_l : (mat == 1) ? Whh_r : Whh_d;
  float v = (k < 64) ? Wih[(size_t)orow * 64 + k] : Whh[(size_t)orow * 512 + (k - 64)];
  wcat2[idx] = (bf16_t)v;
}

__global__ __launch_bounds__(256) void pack_bias_kernel(
    const float* __restrict__ bih_l, const float* __restrict__ bhh_l,
    const float* __restrict__ bih_r, const float* __restrict__ bhh_r,
    const float* __restrict__ bih_d, const float* __restrict__ bhh_d,
    float* __restrict__ biasc) {
  int idx = blockIdx.x * 256 + threadIdx.x;
  if (idx >= 3 * kNG) return;
  int mat = idx / kNG;
  int c = idx - mat * kNG;
  int g = (c >> 4) & 3;
  int u = (c >> 6) * 16 + (c & 15);
  int orow = g * kH + u;
  const float* bi = (mat == 0) ? bih_l : (mat == 1) ? bih_r : bih_d;
  const float* bh = (mat == 0) ? bhh_l : (mat == 1) ? bhh_r : bhh_d;
  biasc[idx] = bi[orow] + bh[orow];
}

__global__ __launch_bounds__(256) void pack_hc_kernel(const float* __restrict__ h0,
                                                      const float* __restrict__ c0,
                                                      bf16_t* __restrict__ hbuf0,
                                                      float* __restrict__ cbuf, int n) {
  int i = blockIdx.x * 256 + threadIdx.x;
  if (i >= n) return;
  hbuf0[i] = (bf16_t)h0[i];
  cbuf[i]  = c0[i];
}

__global__ __launch_bounds__(256) void transpose64_kernel(const bf16_t* __restrict__ feat,
                                                          bf16_t* __restrict__ featT) {
  __shared__ bf16_t tile[64][65];
  const int b = blockIdx.x;
  const bf16_t* src = feat + (size_t)b * kFS;
  bf16_t* dst = featT + (size_t)b * kFS;
  for (int i = threadIdx.x; i < 4096; i += 256) tile[i >> 6][i & 63] = src[i];
  __syncthreads();
  for (int i = threadIdx.x; i < 4096; i += 256) dst[i] = tile[i & 63][i >> 6];
}

// ---------------- feat GEMM (m97-style, verified; part of the best-measured config) ----------------

__global__ __launch_bounds__(256, 4) void gemm_feat_kernel(
    const bf16_t* __restrict__ X, const bf16_t* __restrict__ W,
    const float* __restrict__ b1, bf16_t* __restrict__ feat) {
  __shared__ bf16_t As[128 * 32];
  __shared__ bf16_t Bs[128 * 32];
  const int t = threadIdx.x;
  const int bid = blockIdx.x;
  const int widx = (bid & 7) * 128 + (bid >> 3);
  const int bm = widx & 31, bn = widx >> 5;
  const int w = t >> 6, l = t & 63;
  const int wm = (w >> 1) * 64, wn = (w & 1) * 64;
  const int sr = t >> 2;
  const int skS = ((t & 3) ^ ((t >> 3) & 3)) * 8;
  const int lr = l & 15;
  const int lkS = ((l >> 4) ^ ((l >> 1) & 3)) * 8;
  const int lrow4 = (l >> 4) * 4;

  f32x4 acc[4][4];
#pragma unroll
  for (int i = 0; i < 4; ++i)
#pragma unroll
    for (int j = 0; j < 4; ++j) acc[i][j] = (f32x4){0.f, 0.f, 0.f, 0.f};

  const bf16_t* ga = X + (size_t)(bm * 128 + sr) * kIN + skS;
  const bf16_t* gb = W + (size_t)(bn * 128 + sr) * kIN + skS;
  bf16_t* lA = As + w * 512;
  bf16_t* lB = Bs + w * 512;

  for (int kt = 0; kt < kIN / 32; ++kt) {
    gload16(ga, lA);
    gload16(ga + (size_t)64 * kIN, lA + 2048);
    gload16(gb, lB);
    gload16(gb + (size_t)64 * kIN, lB + 2048);
    ga += 32; gb += 32;
    __syncthreads();
    bfrag a[4], b[4];
#pragma unroll
    for (int mi = 0; mi < 4; ++mi)
      a[mi] = *reinterpret_cast<const bfrag*>(&As[(wm + mi * 16 + lr) * 32 + lkS]);
#pragma unroll
    for (int ni = 0; ni < 4; ++ni)
      b[ni] = *reinterpret_cast<const bfrag*>(&Bs[(wn + ni * 16 + lr) * 32 + lkS]);
#pragma unroll
    for (int mi = 0; mi < 4; ++mi)
#pragma unroll
      for (int ni = 0; ni < 4; ++ni)
        acc[mi][ni] = __builtin_amdgcn_mfma_f32_16x16x32_bf16(a[mi], b[ni], acc[mi][ni], 0, 0, 0);
    __syncthreads();
  }

#pragma unroll
  for (int ni = 0; ni < 4; ++ni) {
    const int col = bn * 128 + wn + ni * 16 + lr;
    const float bb = b1[col];
#pragma unroll
    for (int mi = 0; mi < 4; ++mi) {
#pragma unroll
      for (int r = 0; r < 4; ++r) {
        const int row = bm * 128 + wm + mi * 16 + lrow4 + r;
        float v = acc[mi][ni][r] + bb;
        feat[(size_t)row * kFS + col] = (bf16_t)fmaxf(v, 0.0f);
      }
    }
  }
}

// ---------------- step kernel: 256x256, 8 waves (2Mx4N), B direct-from-global ----------------
// Session-best verified configuration (R9): A via LDS (32 KB dbuf, T2 swizzle);
// B fragments direct from fragment-ordered wcat2 (ping-pong regs, full unroll);
// one raw s_barrier per K-tile, counted vmcnt(8); per-lane gate epilogue (gate=nn,
// unit in-lane by wcat2's column mapping), fp32 c in place.

__global__ __launch_bounds__(512, 1) void lstm_step_kernel(
    const bf16_t* __restrict__ feat, const bf16_t* __restrict__ featT,
    const bf16_t* __restrict__ wcat2, const float* __restrict__ biasc,
    const bf16_t* __restrict__ hin, bf16_t* __restrict__ hout,
    float* __restrict__ cbuf, int s) {
  extern __shared__ __align__(16) char smem[];   // 2 x 32 KB A buffers

  const int t = threadIdx.x;
  const int l = t & 63, w = t >> 6;
  const int wr = w >> 2, wc = w & 3;   // 2M x 4N; wave tile 128 x 64
  const int lr = l & 15, lq = l >> 4;
  const int sx = lr & 7;
  const int srow = l >> 3;
  const int sslot = (l & 7) ^ (srow & 7);

  // grid 512 = 4 cell x 16 bm x 8 bn; XCD swizzle (bijective, 512 % 8 == 0)
  const int bid = blockIdx.x;
  const int widx = (bid & 7) * 64 + (bid >> 3);
  const int cell = widx >> 7;
  const int rwk = widx & 127;
  const int bm = rwk >> 3, bn = rwk & 7;

  const bf16_t* xsrc = (cell < 2) ? feat : featT;
  const int off = ((cell & 1) ? (63 - s) : s) * 64;
  const int mat = (cell < 2) ? cell : 2;
  const bf16_t* hc = hin + (size_t)cell * kB * kH;

  // A staging: 256 rows x 64 K per tile; 512 threads x 4 loads.
  auto stageA = [&](int kt, int buf) {
    bf16_t* base = (bf16_t*)(smem + buf * 32768);
#pragma unroll
    for (int j = 0; j < 4; ++j) {
      const int row0 = j * 64 + w * 8;          // wave-uniform
      bf16_t* dst = base + row0 * 64;
      const bf16_t* src = (kt == 0)
          ? xsrc + (size_t)(bm * 256 + row0 + srow) * kFS + off + sslot * 8
          : hc + (size_t)(bm * 256 + row0 + srow) * kH + (kt - 1) * 64 + sslot * 8;
      gload16(src, dst);
    }
  };

  // B fragment loads: chunk (mat, nb, kt, kk) at elem offset chunkIdx*512 + l*8.
  const size_t wb0 = ((size_t)mat * 128 + bn * 16 + wc * 4) * 9;   // chunk row for nn=0
  auto loadB = [&](int kt, bfrag (&d)[8]) {
#pragma unroll
    for (int nn = 0; nn < 4; ++nn)
#pragma unroll
      for (int kk = 0; kk < 2; ++kk)
        d[nn * 2 + kk] = *reinterpret_cast<const bfrag*>(
            wcat2 + (((wb0 + (size_t)nn * 9 + kt) * 2 + kk) << 9) + l * 8);
  };

  f32x4 acc[8][4];
#pragma unroll
  for (int i = 0; i < 8; ++i)
#pragma unroll
    for (int j = 0; j < 4; ++j) acc[i][j] = (f32x4){0.f, 0.f, 0.f, 0.f};

  bfrag bA[8], bB[8];

  // prologue
  stageA(0, 0);
  loadB(0, bA);
  asm volatile("s_waitcnt vmcnt(0)" ::: "memory");
  __builtin_amdgcn_sched_barrier(0);
  __builtin_amdgcn_s_barrier();

#pragma unroll
  for (int kt = 0; kt < 9; ++kt) {
    const int cur = kt & 1;
    const bf16_t* As_ = (const bf16_t*)(smem + cur * 32768);
    bfrag (&bCur)[8] = (kt & 1) ? bB : bA;
    bfrag (&bNxt)[8] = (kt & 1) ? bA : bB;

    if (kt < 8) stageA(kt + 1, cur ^ 1);

    bfrag a[8];
    // ---- sub-burst 1: mi 0..3 ----
#pragma unroll
    for (int mi = 0; mi < 4; ++mi)
#pragma unroll
      for (int kk = 0; kk < 2; ++kk)
        a[mi * 2 + kk] = *reinterpret_cast<const bfrag*>(
            As_ + (wr * 128 + mi * 16 + lr) * 64 + (((kk * 4 + lq) ^ sx) * 8));
    __builtin_amdgcn_s_setprio(1);
#pragma unroll
    for (int kk = 0; kk < 2; ++kk)
#pragma unroll
      for (int mi = 0; mi < 4; ++mi)
#pragma unroll
        for (int nn = 0; nn < 4; ++nn)
          acc[mi][nn] = mfma16(a[mi * 2 + kk], bCur[nn * 2 + kk], acc[mi][nn]);
    __builtin_amdgcn_s_setprio(0);

    if (kt < 8) loadB(kt + 1, bNxt);   // lands under sub-burst 2 + barrier

    // ---- sub-burst 2: mi 4..7 ----
#pragma unroll
    for (int mi = 0; mi < 4; ++mi)
#pragma unroll
      for (int kk = 0; kk < 2; ++kk)
        a[mi * 2 + kk] = *reinterpret_cast<const bfrag*>(
            As_ + (wr * 128 + 64 + mi * 16 + lr) * 64 + (((kk * 4 + lq) ^ sx) * 8));
    __builtin_amdgcn_s_setprio(1);
#pragma unroll
    for (int kk = 0; kk < 2; ++kk)
#pragma unroll
      for (int mi = 0; mi < 4; ++mi)
#pragma unroll
        for (int nn = 0; nn < 4; ++nn)
          acc[4 + mi][nn] = mfma16(a[mi * 2 + kk], bCur[nn * 2 + kk], acc[4 + mi][nn]);
    __builtin_amdgcn_s_setprio(0);
    __builtin_amdgcn_sched_barrier(0);

    if (kt < 8) {
      asm volatile("s_waitcnt vmcnt(8)" ::: "memory");  // A-stage landed; 8 b-loads in flight
      __builtin_amdgcn_sched_barrier(0);
      __builtin_amdgcn_s_barrier();
    }
  }

  // ---- epilogue: pure per-lane gate fusion (no LDS, no barriers) ----
  const float* biasn = biasc + mat * kNG + bn * 256 + wc * 64;
  const float bb0 = biasn[0 * 16 + lr];
  const float bb1 = biasn[1 * 16 + lr];
  const float bb2 = biasn[2 * 16 + lr];
  const float bb3 = biasn[3 * 16 + lr];
  const int u = (bn * 4 + wc) * 16 + lr;
  const int row0 = bm * 256 + wr * 128 + lq * 4;
#pragma unroll
  for (int mi = 0; mi < 8; ++mi) {
#pragma unroll
    for (int j = 0; j < 4; ++j) {
      const float iv = sigf(acc[mi][0][j] + bb0);
      const float fv = sigf(acc[mi][1][j] + bb1);
      const float gv = tanh_fast(acc[mi][2][j] + bb2);
      const float ov = sigf(acc[mi][3][j] + bb3);
      const int row = row0 + mi * 16 + j;
      const size_t cidx = ((size_t)cell * kB + row) * kH + u;
      const float cn = fv * cbuf[cidx] + iv * gv;
      cbuf[cidx] = cn;
      hout[cidx] = (bf16_t)(ov * tanh_fast(cn));
    }
  }
}

// ---------------- head: wave shuffle reduce ----------------

__global__ __launch_bounds__(256) void head_kernel(const bf16_t* __restrict__ hfin,
                                                   const float* __restrict__ W3,
                                                   const float* __restrict__ b3,
                                                   float* __restrict__ out) {
  const int b = blockIdx.x, t = threadIdx.x;
  const int l = t & 63, w = t >> 6;
  float acc[10];
#pragma unroll
  for (int j = 0; j < 10; ++j) acc[j] = 0.f;
  for (int k = t; k < 2048; k += 256) {
    const int cell = k >> 9, u = k & 511;
    const float hv = (float)hfin[((size_t)cell * kB + b) * kH + u];
#pragma unroll
    for (int j = 0; j < 10; ++j) acc[j] += hv * W3[j * 2048 + k];
  }
#pragma unroll
  for (int j = 0; j < 10; ++j)
#pragma unroll
    for (int o = 32; o > 0; o >>= 1) acc[j] += __shfl_down(acc[j], o, 64);
  __shared__ float wred[4][10];
  if (l == 0)
#pragma unroll
    for (int j = 0; j < 10; ++j) wred[w][j] = acc[j];
  __syncthreads();
  if (t == 0) {
    float logits[10];
#pragma unroll
    for (int j = 0; j < 10; ++j)
      logits[j] = wred[0][j] + wred[1][j] + wred[2][j] + wred[3][j] + b3[j];
    float mx = logits[0];
#pragma unroll
    for (int j = 1; j < 10; ++j) mx = fmaxf(mx, logits[j]);
    float se = 0.f;
#pragma unroll
    for (int j = 0; j < 10; ++j) se += expf(logits[j] - mx);
    const float lse = mx + logf(se);
#pragma unroll
    for (int j = 0; j < 10; ++j) out[(size_t)b * 10 + j] = logits[j] - lse;
  }
}

}  // namespace

extern "C" void kernel_launch(void* const* d_in, const int* in_sizes, int n_in,
                              void* d_out, int out_size, void* d_ws, size_t ws_size,
                              hipStream_t stream) {
  const float* x     = (const float*)d_in[0];
  const float* h0    = (const float*)d_in[1];
  const float* c0    = (const float*)d_in[2];
  const float* W1    = (const float*)d_in[3];
  const float* b1    = (const float*)d_in[4];
  const float* Wih_l = (const float*)d_in[5];
  const float* Whh_l = (const float*)d_in[6];
  const float* bih_l = (const float*)d_in[7];
  const float* bhh_l = (const float*)d_in[8];
  const float* Wih_r = (const float*)d_in[9];
  const float* Whh_r = (const float*)d_in[10];
  const float* bih_r = (const float*)d_in[11];
  const float* bhh_r = (const float*)d_in[12];
  const float* Wih_d = (const float*)d_in[13];
  const float* Whh_d = (const float*)d_in[14];
  const float* bih_d = (const float*)d_in[15];
  const float* bhh_d = (const float*)d_in[16];
  const float* W3    = (const float*)d_in[17];
  const float* b3    = (const float*)d_in[18];
  float* out = (float*)d_out;

  char* p = (char*)d_ws;
  auto take = [&](size_t bytes) {
    char* r = p;
    p += (bytes + 255) & ~(size_t)255;
    return r;
  };
  bf16_t* xb    = (bf16_t*)take((size_t)kB * kIN * 2);   // later reused as featT
  bf16_t* w1b   = (bf16_t*)take((size_t)kFS * kIN * 2);  // later reused as hbuf (2 slots)
  bf16_t* feat  = (bf16_t*)take((size_t)kB * kFS * 2);
  bf16_t* wcat2 = (bf16_t*)take((size_t)3 * 128 * 9 * 2 * 64 * 8 * 2);
  float*  biasc = (float*)take((size_t)3 * kNG * 4);
  float*  cbuf  = (float*)take((size_t)4 * kB * kH * 4);
  bf16_t* featT = xb;   // safe: gemm_feat (reads xb) precedes transpose (writes featT)
  bf16_t* hbuf  = w1b;  // safe: gemm_feat (reads w1b) precedes pack_hc
  const size_t HSZ = (size_t)4 * kB * kH;

  (void)hipFuncSetAttribute(reinterpret_cast<const void*>(&lstm_step_kernel),
                            hipFuncAttributeMaxDynamicSharedMemorySize, 65536);

  f2b4_kernel<<<(kB * kIN / 4) / 256, 256, 0, stream>>>(x, xb, kB * kIN / 4);
  f2b4_kernel<<<(kFS * kIN / 4) / 256, 256, 0, stream>>>(W1, w1b, kFS * kIN / 4);
  gemm_feat_kernel<<<dim3(1024), 256, 0, stream>>>(xb, w1b, b1, feat);
  transpose64_kernel<<<kB, 256, 0, stream>>>(feat, featT);
  {
    const int total = 3 * 128 * 9 * 2 * 64 * 8;
    pack_wcat2_kernel<<<(total + 255) / 256, 256, 0, stream>>>(
        Wih_l, Whh_l, Wih_r, Whh_r, Wih_d, Whh_d, wcat2);
  }
  pack_bias_kernel<<<(3 * kNG + 255) / 256, 256, 0, stream>>>(
      bih_l, bhh_l, bih_r, bhh_r, bih_d, bhh_d, biasc);
  pack_hc_kernel<<<(int)(HSZ / 256), 256, 0, stream>>>(h0, c0, hbuf, cbuf, (int)HSZ);

  for (int s = 0; s < 64; ++s) {
    lstm_step_kernel<<<dim3(512), 512, 65536, stream>>>(
        feat, featT, wcat2, biasc,
        hbuf + (size_t)(s & 1) * HSZ, hbuf + (size_t)((s + 1) & 1) * HSZ, cbuf, s);
  }
  head_kernel<<<kB, 256, 0, stream>>>(hbuf, W3, b3, out);
}